// Round 1
// baseline (384.815 us; speedup 1.0000x reference)
//
#include <hip/hip_runtime.h>
#include <math.h>

// Problem constants (fixed by reference): corr (B=8, HW=4096, H=64, W=64) fp32.
constexpr int Bc      = 8;
constexpr int Hc      = 64;
constexpr int Wc      = 64;
constexpr int HWc     = 4096;          // Hc*Wc
constexpr int KCHUNKS = 8;             // split-K factor for argmax
constexpr int KCHUNK  = HWc / KCHUNKS; // 512
constexpr int PTILE   = 1024;          // pixels per block in k1 (256 thr * float4)

// ---------------------------------------------------------------------------
// Kernel 1: partial argmax over k-chunks.
// grid = Bc * (HWc/PTILE) * KCHUNKS = 8*4*8 = 256 blocks, 256 threads.
// Each thread owns 4 consecutive pixels (float4 loads, fully coalesced).
// Strict '>' keeps the FIRST occurrence of the max (matches jnp.argmax).
// ---------------------------------------------------------------------------
__global__ __launch_bounds__(256) void k_partial_argmax(
        const float* __restrict__ corr,
        float* __restrict__ pmax, int* __restrict__ pidx) {
    int blk = blockIdx.x;
    int kc  = blk & (KCHUNKS - 1);
    int pt  = (blk >> 3) & ((HWc / PTILE) - 1);
    int b   = blk >> 5;
    int pix0 = pt * PTILE + threadIdx.x * 4;

    const float* base = corr + (size_t)b * HWc * HWc + pix0;

    float bm[4] = {-INFINITY, -INFINITY, -INFINITY, -INFINITY};
    int   bi[4] = {0, 0, 0, 0};

    int k0 = kc * KCHUNK;
    #pragma unroll 4
    for (int k = k0; k < k0 + KCHUNK; ++k) {
        float4 v = *reinterpret_cast<const float4*>(base + (size_t)k * HWc);
        if (v.x > bm[0]) { bm[0] = v.x; bi[0] = k; }
        if (v.y > bm[1]) { bm[1] = v.y; bi[1] = k; }
        if (v.z > bm[2]) { bm[2] = v.z; bi[2] = k; }
        if (v.w > bm[3]) { bm[3] = v.w; bi[3] = k; }
    }

    size_t o = ((size_t)(b * KCHUNKS + kc)) * HWc + pix0;
    *reinterpret_cast<float4*>(pmax + o) = make_float4(bm[0], bm[1], bm[2], bm[3]);
    *reinterpret_cast<int4*>(pidx + o)   = make_int4(bi[0], bi[1], bi[2], bi[3]);
}

// ---------------------------------------------------------------------------
// Kernel 2: reduce the KCHUNKS partials to the final argmax index per pixel.
// Iterating kc in increasing order with strict '>' preserves first-occurrence.
// grid = Bc*HWc/256 = 128 blocks.
// ---------------------------------------------------------------------------
__global__ __launch_bounds__(256) void k_reduce_argmax(
        const float* __restrict__ pmax, const int* __restrict__ pidx,
        int* __restrict__ fidx) {
    int g   = blockIdx.x * 256 + threadIdx.x;  // 0 .. 32767
    int b   = g >> 12;
    int pix = g & (HWc - 1);

    float best = -INFINITY;
    int   bidx = 0;
    #pragma unroll
    for (int kc = 0; kc < KCHUNKS; ++kc) {
        int off = ((b * KCHUNKS + kc) << 12) + pix;
        float v = pmax[off];
        if (v > best) { best = v; bidx = pidx[off]; }
    }
    fidx[g] = bidx;
}

// ---------------------------------------------------------------------------
// Kernel 3: out = corr * exp(-((sx-ix)^2+(sy-iy)^2)/50), separable as
// g[sy-iy]*g[sx-ix] with g a 127-entry table (LDS).
// grid = Bc*Hc = 512 blocks (one per (b, sy)), 256 threads.
// iy/ix for the whole b-slice staged once in LDS (8 KB), gy hoisted to regs.
// Pure float4 streaming read+write, coalesced.
// ---------------------------------------------------------------------------
__global__ __launch_bounds__(256) void k_apply(
        const float* __restrict__ corr, const int* __restrict__ fidx,
        float* __restrict__ out) {
    int sy = blockIdx.x & (Hc - 1);
    int b  = blockIdx.x >> 6;

    __shared__ float gtab[128];                 // g[d+63], d in [-63,63]
    __shared__ unsigned char iy[HWc];
    __shared__ unsigned char ix[HWc];

    for (int i = threadIdx.x; i < 128; i += 256) {
        float d = (float)(i - 63);
        gtab[i] = __expf(-d * d * (1.0f / 50.0f));  // 2*sigma^2 = 50
    }
    const int* fb = fidx + b * HWc;
    for (int i = threadIdx.x; i < HWc; i += 256) {
        int id = fb[i];
        iy[i] = (unsigned char)(id >> 6);
        ix[i] = (unsigned char)(id & 63);
    }
    __syncthreads();

    // Each thread owns 16 pixels: p = it*1024 + tid*4 + j. gy (depends only on
    // sy, fixed per block) is precomputed into registers; all indices static.
    float gy[16];
    int   ixr[16];
    #pragma unroll
    for (int it = 0; it < 4; ++it) {
        int p = it * 1024 + threadIdx.x * 4;
        #pragma unroll
        for (int j = 0; j < 4; ++j) {
            gy[it * 4 + j]  = gtab[sy - (int)iy[p + j] + 63];
            ixr[it * 4 + j] = (int)ix[p + j];
        }
    }

    const float* cb = corr + (size_t)b * HWc * HWc + (size_t)sy * Wc * HWc;
    float*       ob = out  + (size_t)b * HWc * HWc + (size_t)sy * Wc * HWc;

    for (int sx = 0; sx < Wc; ++sx) {
        const float* cs = cb + sx * HWc;
        float*       os = ob + sx * HWc;
        #pragma unroll
        for (int it = 0; it < 4; ++it) {
            int p = it * 1024 + threadIdx.x * 4;
            float4 v = *reinterpret_cast<const float4*>(cs + p);
            float4 r;
            r.x = v.x * gy[it * 4 + 0] * gtab[sx - ixr[it * 4 + 0] + 63];
            r.y = v.y * gy[it * 4 + 1] * gtab[sx - ixr[it * 4 + 1] + 63];
            r.z = v.z * gy[it * 4 + 2] * gtab[sx - ixr[it * 4 + 2] + 63];
            r.w = v.w * gy[it * 4 + 3] * gtab[sx - ixr[it * 4 + 3] + 63];
            *reinterpret_cast<float4*>(os + p) = r;
        }
    }
}

extern "C" void kernel_launch(void* const* d_in, const int* in_sizes, int n_in,
                              void* d_out, int out_size, void* d_ws, size_t ws_size,
                              hipStream_t stream) {
    const float* corr = (const float*)d_in[0];
    float* out = (float*)d_out;

    // Workspace layout (2.25 MB total):
    //   pmax : Bc*KCHUNKS*HWc floats (1 MB)
    //   pidx : Bc*KCHUNKS*HWc ints   (1 MB)
    //   fidx : Bc*HWc ints           (128 KB)
    float* pmax = (float*)d_ws;
    int*   pidx = (int*)(pmax + Bc * KCHUNKS * HWc);
    int*   fidx = pidx + Bc * KCHUNKS * HWc;

    k_partial_argmax<<<Bc * (HWc / PTILE) * KCHUNKS, 256, 0, stream>>>(corr, pmax, pidx);
    k_reduce_argmax<<<(Bc * HWc) / 256, 256, 0, stream>>>(pmax, pidx, fidx);
    k_apply<<<Bc * Hc, 256, 0, stream>>>(corr, fidx, out);
}

// Round 3
// 359.746 us; speedup vs baseline: 1.0697x; 1.0697x over previous
//
#include <hip/hip_runtime.h>
#include <math.h>

// Problem constants (fixed by reference): corr (B=8, HW=4096, H=64, W=64) fp32.
constexpr int Bc   = 8;
constexpr int Hc   = 64;
constexpr int Wc   = 64;
constexpr int HWc  = 4096;           // Hc*Wc
constexpr int GRP  = 2;              // batches per group (2*64MB slab fits L3 easily)
constexpr int KCH  = 64;             // split-K chunks for argmax
constexpr int KLEN = HWc / KCH;      // 64 rows per chunk

typedef float f32x4 __attribute__((ext_vector_type(4)));  // native vec for nontemporal

// ---------------------------------------------------------------------------
// Kernel 1: partial argmax over k-chunks, for a group of GRP batches.
// grid = GRP * 4 * KCH = 512 blocks, 256 threads; thread owns 4 pixels (float4).
// Strict '>' + ascending k keeps FIRST occurrence (matches jnp.argmax).
// Loads are normal (allocate in L3) -- k3 re-reads this slab from L3.
// ---------------------------------------------------------------------------
__global__ __launch_bounds__(256) void k_partial_argmax(
        const float* __restrict__ corr, int b0,
        float* __restrict__ pmax, int* __restrict__ pidx) {
    int blk = blockIdx.x;
    int kc  = blk & (KCH - 1);
    int pt  = (blk >> 6) & 3;
    int bl  = blk >> 8;                       // 0..GRP-1
    int b   = b0 + bl;
    int pix0 = pt * 1024 + threadIdx.x * 4;

    const float* base = corr + (size_t)b * HWc * HWc + pix0;

    float bm[4] = {-INFINITY, -INFINITY, -INFINITY, -INFINITY};
    int   bi[4] = {0, 0, 0, 0};

    int k0 = kc * KLEN;
    #pragma unroll 8
    for (int k = k0; k < k0 + KLEN; ++k) {
        float4 v = *reinterpret_cast<const float4*>(base + (size_t)k * HWc);
        if (v.x > bm[0]) { bm[0] = v.x; bi[0] = k; }
        if (v.y > bm[1]) { bm[1] = v.y; bi[1] = k; }
        if (v.z > bm[2]) { bm[2] = v.z; bi[2] = k; }
        if (v.w > bm[3]) { bm[3] = v.w; bi[3] = k; }
    }

    size_t o = ((size_t)(bl * KCH + kc)) * HWc + pix0;
    *reinterpret_cast<float4*>(pmax + o) = make_float4(bm[0], bm[1], bm[2], bm[3]);
    *reinterpret_cast<int4*>(pidx + o)   = make_int4(bi[0], bi[1], bi[2], bi[3]);
}

// ---------------------------------------------------------------------------
// Kernel 2: reduce KCH partials -> final argmax index per pixel (group of GRP).
// grid = GRP*HWc/256 = 32 blocks. Ascending kc + strict '>' = first-occurrence.
// ---------------------------------------------------------------------------
__global__ __launch_bounds__(256) void k_reduce_argmax(
        const float* __restrict__ pmax, const int* __restrict__ pidx,
        int* __restrict__ fidx) {
    int g   = blockIdx.x * 256 + threadIdx.x;   // 0 .. GRP*HWc-1
    int bl  = g >> 12;
    int pix = g & (HWc - 1);

    float best = -INFINITY;
    int   bidx = 0;
    #pragma unroll 8
    for (int kc = 0; kc < KCH; ++kc) {
        int off = ((bl * KCH + kc) << 12) + pix;
        float v = pmax[off];
        if (v > best) { best = v; bidx = pidx[off]; }
    }
    fidx[g] = bidx;
}

// ---------------------------------------------------------------------------
// Kernel 3: out = corr * g[sy-iy] * g[sx-ix], g = 127-entry Gaussian (LDS).
// grid = GRP * 64(sy) * 4(sx quarter) * 4(pixel tile) = 2048 blocks, 256 thr.
// Thread owns 4 pixels (one float4), loops 16 sx values. corr re-read hits L3
// (slab staged by k1); output stored nontemporal to avoid evicting the slab.
// ---------------------------------------------------------------------------
__global__ __launch_bounds__(256) void k_apply(
        const float* __restrict__ corr, int b0, const int* __restrict__ fidx,
        float* __restrict__ out) {
    int blk  = blockIdx.x;
    int bl   = blk >> 10;
    int rest = blk & 1023;
    int sy   = rest >> 4;
    int sxq  = (rest >> 2) & 3;
    int pt   = rest & 3;
    int b    = b0 + bl;

    __shared__ float gtab[128];                  // g[d+63], d in [-63,63]
    if (threadIdx.x < 128) {
        float d = (float)((int)threadIdx.x - 63);
        gtab[threadIdx.x] = __expf(-d * d * (1.0f / 50.0f));   // 2*sigma^2 = 50
    }
    __syncthreads();

    int p0 = pt * 1024 + threadIdx.x * 4;
    int4 id = *reinterpret_cast<const int4*>(fidx + bl * HWc + p0);

    // gy per pixel (sy fixed per block); gx index base ic = 63 - ix, so the
    // LDS address per element is gtab[sx + ic] with ic loop-invariant.
    float gy0 = gtab[sy - (id.x >> 6) + 63];
    float gy1 = gtab[sy - (id.y >> 6) + 63];
    float gy2 = gtab[sy - (id.z >> 6) + 63];
    float gy3 = gtab[sy - (id.w >> 6) + 63];
    int ic0 = 63 - (id.x & 63);
    int ic1 = 63 - (id.y & 63);
    int ic2 = 63 - (id.z & 63);
    int ic3 = 63 - (id.w & 63);

    size_t rowbase = (size_t)b * HWc * HWc + (size_t)(sy * Wc + sxq * 16) * HWc + p0;
    const float* cs = corr + rowbase;
    float*       os = out  + rowbase;

    #pragma unroll
    for (int s = 0; s < 16; ++s) {
        int sx = sxq * 16 + s;
        float4 v = *reinterpret_cast<const float4*>(cs + (size_t)s * HWc);
        f32x4 r;
        r.x = v.x * gy0 * gtab[sx + ic0];
        r.y = v.y * gy1 * gtab[sx + ic1];
        r.z = v.z * gy2 * gtab[sx + ic2];
        r.w = v.w * gy3 * gtab[sx + ic3];
        __builtin_nontemporal_store(r, reinterpret_cast<f32x4*>(os + (size_t)s * HWc));
    }
}

extern "C" void kernel_launch(void* const* d_in, const int* in_sizes, int n_in,
                              void* d_out, int out_size, void* d_ws, size_t ws_size,
                              hipStream_t stream) {
    const float* corr = (const float*)d_in[0];
    float* out = (float*)d_out;

    // Workspace (reused per group): pmax 2MB, pidx 2MB, fidx 32KB.
    float* pmax = (float*)d_ws;
    int*   pidx = (int*)(pmax + GRP * KCH * HWc);
    int*   fidx = pidx + GRP * KCH * HWc;

    for (int g = 0; g < Bc / GRP; ++g) {
        int b0 = g * GRP;
        k_partial_argmax<<<GRP * 4 * KCH, 256, 0, stream>>>(corr, b0, pmax, pidx);
        k_reduce_argmax<<<GRP * HWc / 256, 256, 0, stream>>>(pmax, pidx, fidx);
        k_apply<<<GRP * 1024, 256, 0, stream>>>(corr, b0, fidx, out);
    }
}

// Round 6
// 269.585 us; speedup vs baseline: 1.4274x; 1.3344x over previous
//
#include <hip/hip_runtime.h>
#include <math.h>

// corr: (B=8, HW=4096, H=64, W=64) fp32. out same shape.
// out[b,s,p] = corr[b,s,p] * g[sy-iy(p)] * g[sx-ix(p)], idx(p)=argmax_s corr[b,s,p].
constexpr int Bc    = 8;
constexpr int HWc   = 4096;
constexpr int NTHR  = 512;
constexpr int PXB   = 16;                  // pixels per block
constexpr int NBLK  = Bc * HWc / PXB;      // 2048
constexpr int RPT   = 32;                  // rows per thread (4096 / 128 j-threads)

typedef float  f32x4 __attribute__((ext_vector_type(4)));
typedef __fp16 h16x2 __attribute__((ext_vector_type(2)));

__device__ __forceinline__ unsigned monokey(float f) {
    unsigned u = __float_as_uint(f);
    return u ^ ((unsigned)(((int)u) >> 31) | 0x80000000u);
}
__device__ __forceinline__ unsigned pack2h(float a, float b) {
    h16x2 h = __builtin_amdgcn_cvt_pkrtz(a, b);     // 2xf32 -> 2xf16 (RTZ), 1 instr
    return *reinterpret_cast<unsigned*>(&h);
}

// One block owns 16 pixels (one batch). Single HBM read of its column strip:
//   pass1: fp32 argmax in regs (exact) + fp16 copy of the strip in regs.
//   reduce: packed (monokey<<32 | 4095-idx) u64, shfl-xor within wave, then
//           LDS atomicMax (max is order-independent -> deterministic;
//           larger 4095-idx wins ties == first occurrence, matches jnp.argmax).
//   pass2: multiply reg-resident fp16 data by separable Gaussian table, write.
__global__ __launch_bounds__(NTHR, 2) void k_fused(
        const float* __restrict__ corr, float* __restrict__ out) {
    // Swizzle so blocks u and u+8 (same XCD under round-robin dispatch) own
    // ADJACENT 16-pixel groups: the two halves of each 128B line are fetched
    // by co-resident blocks on one XCD L2 -> no over-fetch at 64B strip width.
    unsigned u   = blockIdx.x;
    unsigned gpg = (((u & 7) | ((u >> 4) << 3)) << 1) | ((u >> 3) & 1);  // bijection
    int b    = gpg >> 8;
    int pix0 = (gpg & 255) * PXB;

    int q = threadIdx.x & 3;      // pixel quad: pixels pix0 + q*4 .. +3
    int j = threadIdx.x >> 2;     // row phase: rows k = j + 128*i, i in [0,32)

    __shared__ float gtab[128];                    // g[d+63], d in [-63,63]
    __shared__ unsigned long long slot[PXB];
    if (threadIdx.x < 128) {
        float d = (float)((int)threadIdx.x - 63);
        gtab[threadIdx.x] = __expf(-d * d * (1.0f / 50.0f));   // 2*sigma^2 = 50
    }
    if (threadIdx.x < PXB) slot[threadIdx.x] = 0ull;
    __syncthreads();

    const float* src = corr + (size_t)b * HWc * HWc + (size_t)j * HWc + pix0 + q * 4;

    unsigned dat[RPT * 2];        // strip copy, fp16x2-packed (64 VGPRs)
    float bm0 = -INFINITY, bm1 = -INFINITY, bm2 = -INFINITY, bm3 = -INFINITY;
    int   bi0 = 0, bi1 = 0, bi2 = 0, bi3 = 0;

    #pragma unroll
    for (int c = 0; c < 4; ++c) {                  // chunks of 8 rows: deep MLP
        float4 v[8];
        #pragma unroll
        for (int t = 0; t < 8; ++t)
            v[t] = *reinterpret_cast<const float4*>(src + (size_t)(c * 8 + t) * 128 * HWc);
        #pragma unroll
        for (int t = 0; t < 8; ++t) {
            int i = c * 8 + t;
            int k = j + 128 * i;
            if (v[t].x > bm0) { bm0 = v[t].x; bi0 = k; }
            if (v[t].y > bm1) { bm1 = v[t].y; bi1 = k; }
            if (v[t].z > bm2) { bm2 = v[t].z; bi2 = k; }
            if (v[t].w > bm3) { bm3 = v[t].w; bi3 = k; }
            dat[i * 2]     = pack2h(v[t].x, v[t].y);
            dat[i * 2 + 1] = pack2h(v[t].z, v[t].w);
        }
    }

    // ---- block argmax reduce (exact fp32 keys) ----
    unsigned long long key[4];
    key[0] = ((unsigned long long)monokey(bm0) << 32) | (unsigned)(4095 - bi0);
    key[1] = ((unsigned long long)monokey(bm1) << 32) | (unsigned)(4095 - bi1);
    key[2] = ((unsigned long long)monokey(bm2) << 32) | (unsigned)(4095 - bi2);
    key[3] = ((unsigned long long)monokey(bm3) << 32) | (unsigned)(4095 - bi3);
    #pragma unroll
    for (int m = 4; m <= 32; m <<= 1) {            // reduce over j-bits in wave
        #pragma unroll
        for (int e = 0; e < 4; ++e) {
            unsigned long long o = __shfl_xor(key[e], m, 64);
            if (o > key[e]) key[e] = o;
        }
    }
    if ((threadIdx.x & 63) < 4) {                  // one lane per q per wave
        #pragma unroll
        for (int e = 0; e < 4; ++e) atomicMax(&slot[q * 4 + e], key[e]);
    }
    __syncthreads();

    // ---- pass2: separable Gaussian from table, multiply, stream out ----
    int sx = j & 63;                               // sx = k & 63 is j-invariant
    float gx[4];
    int   gybase[4];
    #pragma unroll
    for (int e = 0; e < 4; ++e) {
        int idx = 4095 - (int)(unsigned)(slot[q * 4 + e] & 0xFFFFFFFFull);
        int iy = idx >> 6, ix = idx & 63;
        gx[e]     = gtab[sx - ix + 63];
        gybase[e] = 63 - iy + (j >> 6);            // gy(i) = gtab[gybase + 2*i]
    }

    float* dst = out + (size_t)b * HWc * HWc + (size_t)j * HWc + pix0 + q * 4;
    #pragma unroll
    for (int i = 0; i < RPT; ++i) {
        h16x2 lo = *reinterpret_cast<h16x2*>(&dat[i * 2]);
        h16x2 hi = *reinterpret_cast<h16x2*>(&dat[i * 2 + 1]);
        f32x4 r;
        r.x = (float)lo.x * gx[0] * gtab[gybase[0] + 2 * i];
        r.y = (float)lo.y * gx[1] * gtab[gybase[1] + 2 * i];
        r.z = (float)hi.x * gx[2] * gtab[gybase[2] + 2 * i];
        r.w = (float)hi.y * gx[3] * gtab[gybase[3] + 2 * i];
        *reinterpret_cast<f32x4*>(dst + (size_t)i * 128 * HWc) = r;
    }
}

extern "C" void kernel_launch(void* const* d_in, const int* in_sizes, int n_in,
                              void* d_out, int out_size, void* d_ws, size_t ws_size,
                              hipStream_t stream) {
    const float* corr = (const float*)d_in[0];
    float* out = (float*)d_out;
    k_fused<<<NBLK, NTHR, 0, stream>>>(corr, out);
}

// Round 7
// 257.858 us; speedup vs baseline: 1.4924x; 1.0455x over previous
//
#include <hip/hip_runtime.h>
#include <math.h>

// corr: (B=8, HW=4096, H=64, W=64) fp32. out same shape.
// out[b,s,p] = corr[b,s,p] * g[sy-iy(p)] * g[sx-ix(p)], idx(p)=argmax_s corr[b,s,p].
constexpr int Bc    = 8;
constexpr int HWc   = 4096;
constexpr int NTHR  = 1024;
constexpr int PXB   = 32;                  // pixels per block -> 128B strip width
constexpr int NBLK  = Bc * HWc / PXB;      // 1024
constexpr int RPT   = 32;                  // rows per thread (4096 / 128 j-threads)

typedef float  f32x4 __attribute__((ext_vector_type(4)));
typedef __fp16 h16x2 __attribute__((ext_vector_type(2)));

__device__ __forceinline__ unsigned monokey(float f) {
    unsigned u = __float_as_uint(f);
    return u ^ ((unsigned)(((int)u) >> 31) | 0x80000000u);
}
__device__ __forceinline__ unsigned pack2h(float a, float b) {
    h16x2 h = __builtin_amdgcn_cvt_pkrtz(a, b);     // 2xf32 -> 2xf16 (RTZ), 1 instr
    return *reinterpret_cast<unsigned*>(&h);
}

// One block owns 32 pixels (128B strip -> every global segment is a full
// 128B line; no over-fetch, no cross-block concurrency assumption).
//   pass1: fp32 argmax in regs (exact) + fp16 copy of the strip in regs.
//   reduce: packed (monokey<<32 | 4095-idx) u64; shfl-xor over the 3 j-bits
//           in-wave, then LDS atomicMax (order-independent; larger 4095-idx
//           wins ties == first occurrence, matches jnp.argmax).
//   pass2: multiply reg-resident fp16 by separable Gaussian table, stream out.
__global__ __launch_bounds__(NTHR, 4) void k_fused(
        const float* __restrict__ corr, float* __restrict__ out) {
    int b    = blockIdx.x >> 7;
    int pix0 = (blockIdx.x & 127) * PXB;

    int q = threadIdx.x & 7;      // pixel quad: pixels pix0 + q*4 .. +3
    int j = threadIdx.x >> 3;     // row phase: rows k = j + 128*i, i in [0,32)

    __shared__ float gtab[128];                    // g[d+63], d in [-63,63]
    __shared__ unsigned long long slot[PXB];
    if (threadIdx.x < 128) {
        float d = (float)((int)threadIdx.x - 63);
        gtab[threadIdx.x] = __expf(-d * d * (1.0f / 50.0f));   // 2*sigma^2 = 50
    }
    if (threadIdx.x < PXB) slot[threadIdx.x] = 0ull;
    __syncthreads();

    const float* src = corr + (size_t)b * HWc * HWc + (size_t)j * HWc + pix0 + q * 4;

    unsigned dat[RPT * 2];        // strip copy, fp16x2-packed (64 VGPRs)
    float bm0 = -INFINITY, bm1 = -INFINITY, bm2 = -INFINITY, bm3 = -INFINITY;
    int   bi0 = 0, bi1 = 0, bi2 = 0, bi3 = 0;

    #pragma unroll
    for (int c = 0; c < 8; ++c) {                  // chunks of 4 rows
        float4 v[4];
        #pragma unroll
        for (int t = 0; t < 4; ++t)
            v[t] = *reinterpret_cast<const float4*>(src + (size_t)(c * 4 + t) * 128 * HWc);
        #pragma unroll
        for (int t = 0; t < 4; ++t) {
            int i = c * 4 + t;
            int k = j + 128 * i;
            if (v[t].x > bm0) { bm0 = v[t].x; bi0 = k; }
            if (v[t].y > bm1) { bm1 = v[t].y; bi1 = k; }
            if (v[t].z > bm2) { bm2 = v[t].z; bi2 = k; }
            if (v[t].w > bm3) { bm3 = v[t].w; bi3 = k; }
            dat[i * 2]     = pack2h(v[t].x, v[t].y);
            dat[i * 2 + 1] = pack2h(v[t].z, v[t].w);
        }
    }

    // ---- block argmax reduce (exact fp32 keys) ----
    unsigned long long key[4];
    key[0] = ((unsigned long long)monokey(bm0) << 32) | (unsigned)(4095 - bi0);
    key[1] = ((unsigned long long)monokey(bm1) << 32) | (unsigned)(4095 - bi1);
    key[2] = ((unsigned long long)monokey(bm2) << 32) | (unsigned)(4095 - bi2);
    key[3] = ((unsigned long long)monokey(bm3) << 32) | (unsigned)(4095 - bi3);
    #pragma unroll
    for (int m = 8; m <= 32; m <<= 1) {            // reduce over j-bits in wave
        #pragma unroll
        for (int e = 0; e < 4; ++e) {
            unsigned long long o = __shfl_xor(key[e], m, 64);
            if (o > key[e]) key[e] = o;
        }
    }
    if ((threadIdx.x & 63) < 8) {                  // lane==q for these lanes
        #pragma unroll
        for (int e = 0; e < 4; ++e) atomicMax(&slot[q * 4 + e], key[e]);
    }
    __syncthreads();

    // ---- pass2: separable Gaussian from table, multiply, stream out ----
    int sx = j & 63;                               // sx = k & 63 is j-invariant
    float gx[4];
    int   gybase[4];
    #pragma unroll
    for (int e = 0; e < 4; ++e) {
        int idx = 4095 - (int)(unsigned)(slot[q * 4 + e] & 0xFFFFFFFFull);
        int iy = idx >> 6, ix = idx & 63;
        gx[e]     = gtab[sx - ix + 63];
        gybase[e] = 63 - iy + (j >> 6);            // gy(i) = gtab[gybase + 2*i]
    }

    float* dst = out + (size_t)b * HWc * HWc + (size_t)j * HWc + pix0 + q * 4;
    #pragma unroll
    for (int i = 0; i < RPT; ++i) {
        h16x2 lo = *reinterpret_cast<h16x2*>(&dat[i * 2]);
        h16x2 hi = *reinterpret_cast<h16x2*>(&dat[i * 2 + 1]);
        f32x4 r;
        r.x = (float)lo.x * gx[0] * gtab[gybase[0] + 2 * i];
        r.y = (float)lo.y * gx[1] * gtab[gybase[1] + 2 * i];
        r.z = (float)hi.x * gx[2] * gtab[gybase[2] + 2 * i];
        r.w = (float)hi.y * gx[3] * gtab[gybase[3] + 2 * i];
        __builtin_nontemporal_store(r, reinterpret_cast<f32x4*>(dst + (size_t)i * 128 * HWc));
    }
}

extern "C" void kernel_launch(void* const* d_in, const int* in_sizes, int n_in,
                              void* d_out, int out_size, void* d_ws, size_t ws_size,
                              hipStream_t stream) {
    const float* corr = (const float*)d_in[0];
    float* out = (float*)d_out;
    k_fused<<<NBLK, NTHR, 0, stream>>>(corr, out);
}